// Round 9
// baseline (12.810 us; speedup 1.0000x reference)
//
#include <hip/hip_runtime.h>
#include <math.h>

// ESPRIT DOA: only frames 120..123, bins 13..31, 4 mics are consumed by the
// reference. Single workgroup, two barriers, all-float latency pipeline.
// x is (T, 4) row-major float -> one sample (4 mics) == one float4.
// r9: stage-1 bin-PAIRING (each wave computes 2 bins per LDS read stream);
// halves the dominant single-CU LDS b128 traffic vs r8.

#define NFFT   512
#define KLO    13
#define NK     19        // bins 13..31  (400 <= f < 1000, f = k*31.25)
#define NTT    4         // frames 120..123
#define NMIC   4
#define XBASE  30464     // T_START*HOP - NFFT/2
#define PI_F   3.14159265358979f

// xw LDS layout (pre-windowed frames, float4 per sample, skewed):
//   phys(t,n) = t*2116 + (n>>5)*132 + (n&31)*4   (dwords, 16B-aligned)
// frame stride 2116 and chunk stride 132 are ≡4 (mod 32): the 64 lanes of a
// wave land 8-per-4-bank-window each iteration (the balanced 1024B/128B floor).
#define FRM_STRIDE 2116
#define CHK_STRIDE 132
#define XW_SIZE    8456

struct cf { float x, y; };
__device__ inline cf cadd(cf a, cf b){ return {a.x+b.x, a.y+b.y}; }
__device__ inline cf csub(cf a, cf b){ return {a.x-b.x, a.y-b.y}; }
__device__ inline cf cmul(cf a, cf b){ return {a.x*b.x - a.y*b.y, a.x*b.y + a.y*b.x}; }
__device__ inline cf cmulc(cf a, cf b){ return {a.x*b.x + a.y*b.y, a.y*b.x - a.x*b.y}; } // a*conj(b)
__device__ inline cf cscale(cf a, float s){ return {a.x*s, a.y*s}; }
__device__ inline cf csqrtf_c(cf z){
    float r = sqrtf(z.x*z.x + z.y*z.y);
    float u = sqrtf(fmaxf(0.5f*(r + z.x), 0.0f));
    float v = sqrtf(fmaxf(0.5f*(r - z.x), 0.0f));
    if (z.y < 0.0f) v = -v;
    return {u, v};
}

__global__ __launch_bounds__(640)
void esprit_kernel(const float* __restrict__ x, float* __restrict__ out)
{
    __shared__ __align__(16) float xw[XW_SIZE];
    __shared__ float XsR[NK + 1][NTT][NMIC], XsI[NK + 1][NTT][NMIC]; // +1 pad bin

    const int tid = threadIdx.x;

    // ---- stage 0: coalesced float4 staging + window, into skewed LDS ------
    // xw(t,n) = sin(pi*n/512) * x[XBASE + t*256 + n][:]   (2048 float4 total)
    for (int e = tid; e < NTT * NFFT; e += 640) {
        int t = e >> 9;
        int n = e & 511;
        float4 v = ((const float4*)x)[XBASE + t * 256 + n];
        float w = __sinf((float)n * (PI_F / 512.0f));      // sqrt-hann
        v.x *= w; v.y *= w; v.z *= w; v.w *= w;
        *(float4*)&xw[t * FRM_STRIDE + (n >> 5) * CHK_STRIDE + (n & 31) * 4] = v;
    }
    __syncthreads();

    // ---- stage 1: wave w = bin pair (2w, 2w+1); lane = t*16 + p -----------
    // p = 16 sample-parts of 32; each float4 read feeds BOTH bins.
    {
        const int w    = tid >> 6;           // 0..9
        const int lane = tid & 63;
        const int t    = lane >> 4;          // frame 0..3
        const int p    = lane & 15;          // part: samples [32p, 32p+32)
        const int kk0  = w << 1;             // bins kk0, kk0+1 (kk=19 -> pad)
        const int k0   = KLO + kk0;
        const int k1   = k0 + 1;
        const int n0   = p << 5;

        float cr0, ci0, wc0, ws0, cr1, ci1, wc1, ws1;
        __sincosf((float)((k0 * n0) & 511) * (-2.0f * PI_F / 512.0f), &ci0, &cr0);
        __sincosf((float)k0               * (-2.0f * PI_F / 512.0f), &ws0, &wc0);
        __sincosf((float)((k1 * n0) & 511) * (-2.0f * PI_F / 512.0f), &ci1, &cr1);
        __sincosf((float)k1               * (-2.0f * PI_F / 512.0f), &ws1, &wc1);

        float ar0=0,ar1=0,ar2=0,ar3=0, ai0=0,ai1=0,ai2=0,ai3=0;   // bin kk0
        float br0=0,br1=0,br2=0,br3=0, bi0=0,bi1=0,bi2=0,bi3=0;   // bin kk0+1
        const int boff = t * FRM_STRIDE + p * CHK_STRIDE;   // 16B-aligned
        #pragma unroll 8
        for (int i = 0; i < 32; ++i) {
            float4 v = *(const float4*)&xw[boff + 4*i];
            ar0 = fmaf(v.x, cr0, ar0); ai0 = fmaf(v.x, ci0, ai0);
            ar1 = fmaf(v.y, cr0, ar1); ai1 = fmaf(v.y, ci0, ai1);
            ar2 = fmaf(v.z, cr0, ar2); ai2 = fmaf(v.z, ci0, ai2);
            ar3 = fmaf(v.w, cr0, ar3); ai3 = fmaf(v.w, ci0, ai3);
            br0 = fmaf(v.x, cr1, br0); bi0 = fmaf(v.x, ci1, bi0);
            br1 = fmaf(v.y, cr1, br1); bi1 = fmaf(v.y, ci1, bi1);
            br2 = fmaf(v.z, cr1, br2); bi2 = fmaf(v.z, ci1, bi2);
            br3 = fmaf(v.w, cr1, br3); bi3 = fmaf(v.w, ci1, bi3);
            float n0r = fmaf(cr0, wc0, -(ci0 * ws0));
            float n0i = fmaf(cr0, ws0,  (ci0 * wc0));
            cr0 = n0r; ci0 = n0i;
            float n1r = fmaf(cr1, wc1, -(ci1 * ws1));
            float n1i = fmaf(cr1, ws1,  (ci1 * wc1));
            cr1 = n1r; ci1 = n1i;
        }
        // reduce the 16 parts (stays within the 16-lane frame group)
        #pragma unroll
        for (int mask = 1; mask < 16; mask <<= 1) {
            ar0 += __shfl_xor(ar0, mask); ai0 += __shfl_xor(ai0, mask);
            ar1 += __shfl_xor(ar1, mask); ai1 += __shfl_xor(ai1, mask);
            ar2 += __shfl_xor(ar2, mask); ai2 += __shfl_xor(ai2, mask);
            ar3 += __shfl_xor(ar3, mask); ai3 += __shfl_xor(ai3, mask);
            br0 += __shfl_xor(br0, mask); bi0 += __shfl_xor(bi0, mask);
            br1 += __shfl_xor(br1, mask); bi1 += __shfl_xor(bi1, mask);
            br2 += __shfl_xor(br2, mask); bi2 += __shfl_xor(bi2, mask);
            br3 += __shfl_xor(br3, mask); bi3 += __shfl_xor(bi3, mask);
        }
        if (p == 0) {
            XsR[kk0][t][0] = ar0; XsI[kk0][t][0] = ai0;
            XsR[kk0][t][1] = ar1; XsI[kk0][t][1] = ai1;
            XsR[kk0][t][2] = ar2; XsI[kk0][t][2] = ai2;
            XsR[kk0][t][3] = ar3; XsI[kk0][t][3] = ai3;
            XsR[kk0+1][t][0] = br0; XsI[kk0+1][t][0] = bi0;   // kk=19 -> pad row
            XsR[kk0+1][t][1] = br1; XsI[kk0+1][t][1] = bi1;
            XsR[kk0+1][t][2] = br2; XsI[kk0+1][t][2] = bi2;
            XsR[kk0+1][t][3] = br3; XsI[kk0+1][t][3] = bi3;
        }
    }
    __syncthreads();

    // ---- stage 2: per-frequency ESPRIT on wave 0, then in-wave mean -------
    float asum = 0.0f;
    if (tid < 64) {
        if (tid < NK) {
            cf Xm[NMIC][NTT];
            for (int m = 0; m < NMIC; ++m)
                for (int t = 0; t < NTT; ++t)
                    Xm[m][t] = { XsR[tid][t][m], XsI[tid][t][m] };

            // R = (1/4) Xs Xs^H
            cf R[4][4];
            for (int i = 0; i < 4; ++i)
                for (int j = 0; j < 4; ++j) {
                    cf acc = {0.f, 0.f};
                    for (int t = 0; t < 4; ++t) acc = cadd(acc, cmulc(Xm[i][t], Xm[j][t]));
                    R[i][j] = cscale(acc, 0.25f);
                }

            // one orthogonal-iteration step -> dominant 2-D subspace
            // (phi eigvals similarity-invariant; lam3/lam2 ~ 1e-8 at -80 dB
            //  noise; validated absmax 0.0 in rounds 6/7/8)
            cf Q[4][2], Y[4][2];
            for (int i = 0; i < 4; ++i) { Y[i][0] = R[i][0]; Y[i][1] = R[i][1]; }
            float nrm0 = 0.f;
            for (int i = 0; i < 4; ++i) nrm0 += Y[i][0].x*Y[i][0].x + Y[i][0].y*Y[i][0].y;
            float in0 = __builtin_amdgcn_rsqf(nrm0);
            for (int i = 0; i < 4; ++i) Q[i][0] = cscale(Y[i][0], in0);
            cf pr = {0.f, 0.f};
            for (int i = 0; i < 4; ++i) pr = cadd(pr, cmulc(Y[i][1], Q[i][0]));  // Q0^H Y1
            for (int i = 0; i < 4; ++i) Q[i][1] = csub(Y[i][1], cmul(pr, Q[i][0]));
            float nrm1 = 0.f;
            for (int i = 0; i < 4; ++i) nrm1 += Q[i][1].x*Q[i][1].x + Q[i][1].y*Q[i][1].y;
            float in1 = __builtin_amdgcn_rsqf(nrm1);
            for (int i = 0; i < 4; ++i) Q[i][1] = cscale(Q[i][1], in1);

            // A = s0^H s0 (Hermitian), B = s0^H s1 ; s0 = rows 0..2, s1 = rows 1..3
            float a00 = 0.f, a11 = 0.f;
            cf a01 = {0.f, 0.f};
            cf B[2][2] = { { {0,0}, {0,0} }, { {0,0}, {0,0} } };
            for (int i = 0; i < 3; ++i) {
                a00 += Q[i][0].x*Q[i][0].x + Q[i][0].y*Q[i][0].y;
                a11 += Q[i][1].x*Q[i][1].x + Q[i][1].y*Q[i][1].y;
                a01 = cadd(a01, cmulc(Q[i][1], Q[i][0]));      // conj(Q0)*Q1
                for (int r2 = 0; r2 < 2; ++r2)
                    for (int c2 = 0; c2 < 2; ++c2)
                        B[r2][c2] = cadd(B[r2][c2], cmulc(Q[i+1][c2], Q[i][r2]));
            }
            float detA = a00*a11 - (a01.x*a01.x + a01.y*a01.y);
            float inv  = __builtin_amdgcn_rcpf(detA);
            cf na01  = { -a01.x, -a01.y };
            cf na01c = { -a01.x,  a01.y };
            cf phi00 = cscale(cadd(cscale(B[0][0], a11), cmul(na01,  B[1][0])), inv);
            cf phi01 = cscale(cadd(cscale(B[0][1], a11), cmul(na01,  B[1][1])), inv);
            cf phi10 = cscale(cadd(cmul(na01c, B[0][0]), cscale(B[1][0], a00)), inv);
            cf phi11 = cscale(cadd(cmul(na01c, B[0][1]), cscale(B[1][1], a00)), inv);

            cf tr = cadd(phi00, phi11);
            cf dt = csub(cmul(phi00, phi11), cmul(phi01, phi10));
            cf d2 = csub(cmul(tr, tr), cscale(dt, 4.0f));
            cf disc = csqrtf_c(d2);
            cf lam0 = cscale(cadd(tr, disc), 0.5f);
            cf lam1 = cscale(csub(tr, disc), 0.5f);

            float f     = 31.25f * (float)(KLO + tid);
            float scale = 343.0f / (2.0f * PI_F * f * 0.08f);
            float ph0 = atan2f(lam0.y, lam0.x);
            float ph1 = atan2f(lam1.y, lam1.x);
            float g0 = fminf(fmaxf(ph0 * scale, -1.0f), 1.0f);
            float g1 = fminf(fmaxf(ph1 * scale, -1.0f), 1.0f);
            asum = (asinf(g0) + asinf(g1)) * (180.0f / PI_F);
        }
        // in-wave mean over the 19 bins (lanes >= 19 contribute 0)
        #pragma unroll
        for (int mask = 32; mask >= 1; mask >>= 1)
            asum += __shfl_xor(asum, mask);
        if (tid == 0) out[0] = asum * (1.0f / 38.0f);
    }
}

extern "C" void kernel_launch(void* const* d_in, const int* in_sizes, int n_in,
                              void* d_out, int out_size, void* d_ws, size_t ws_size,
                              hipStream_t stream)
{
    const float* x = (const float*)d_in[0];
    float* out = (float*)d_out;
    esprit_kernel<<<1, 640, 0, stream>>>(x, out);
}

// Round 10
// 11.575 us; speedup vs baseline: 1.1067x; 1.1067x over previous
//
#include <hip/hip_runtime.h>
#include <math.h>

// ESPRIT DOA: only frames 120..123, bins 13..31, 4 mics are consumed by the
// reference. Single workgroup, two barriers, all-float latency pipeline.
// x is (T, 4) row-major float -> one sample (4 mics) == one float4.
// FINAL = round-8 structure (measured best, 11.4 us):
//   - LDS-staged pre-windowed frames (coalesced float4 + hw __sinf)
//   - 76 (k,t) bins x 8 sample-parts, in-register twiddle rotation
//   - 3-step butterfly reduce, Xs via LDS
//   - stage 2 on one wave: 1 Gram-Schmidt step, native rcp/rsq, in-wave mean
// Measured A/B history: direct-global DFT (r3) -27%, redundant per-lane
// ESPRIT (r6) -15%, multi-WG + memset node (r7) -34%, bin-pairing (r9) -11%.

#define NFFT   512
#define KLO    13
#define NK     19        // bins 13..31  (400 <= f < 1000, f = k*31.25)
#define NTT    4         // frames 120..123
#define NMIC   4
#define XBASE  30464     // T_START*HOP - NFFT/2
#define PI_F   3.14159265358979f

// xw LDS layout (pre-windowed frames, float, mic-interleaved, skewed):
//   phys(t,n) = t*2084 + (n>>6)*260 + (n&63)*4      (dword units, 16B-aligned)
// frame stride 2084 and chunk stride 260 are ≡4 (mod 32) so per-lane
// ds_read_b128 bank-groups spread instead of stacking.
#define FRM_STRIDE 2084
#define CHK_STRIDE 260
#define XW_SIZE    8328

struct cf { float x, y; };
__device__ inline cf cadd(cf a, cf b){ return {a.x+b.x, a.y+b.y}; }
__device__ inline cf csub(cf a, cf b){ return {a.x-b.x, a.y-b.y}; }
__device__ inline cf cmul(cf a, cf b){ return {a.x*b.x - a.y*b.y, a.x*b.y + a.y*b.x}; }
__device__ inline cf cmulc(cf a, cf b){ return {a.x*b.x + a.y*b.y, a.y*b.x - a.x*b.y}; } // a*conj(b)
__device__ inline cf cscale(cf a, float s){ return {a.x*s, a.y*s}; }
__device__ inline cf csqrtf_c(cf z){
    float r = sqrtf(z.x*z.x + z.y*z.y);
    float u = sqrtf(fmaxf(0.5f*(r + z.x), 0.0f));
    float v = sqrtf(fmaxf(0.5f*(r - z.x), 0.0f));
    if (z.y < 0.0f) v = -v;
    return {u, v};
}

__global__ __launch_bounds__(640)
void esprit_kernel(const float* __restrict__ x, float* __restrict__ out)
{
    __shared__ __align__(16) float xw[XW_SIZE];
    __shared__ float XsR[NK][NTT][NMIC], XsI[NK][NTT][NMIC];

    const int tid = threadIdx.x;

    // ---- stage 0: coalesced float4 staging + window, into skewed LDS ------
    // xw(t,n) = sin(pi*n/512) * x[XBASE + t*256 + n][:]   (2048 float4 total)
    for (int e = tid; e < NTT * NFFT; e += 640) {
        int t = e >> 9;
        int n = e & 511;
        float4 v = ((const float4*)x)[XBASE + t * 256 + n];
        float w = __sinf((float)n * (PI_F / 512.0f));      // sqrt-hann
        v.x *= w; v.y *= w; v.z *= w; v.w *= w;
        *(float4*)&xw[t * FRM_STRIDE + (n >> 6) * CHK_STRIDE + (n & 63) * 4] = v;
    }
    __syncthreads();

    // ---- stage 1: 76 (k,t) bins x 8 sample-parts, rotation recurrence -----
    if (tid < 608) {
        const int bin = tid >> 3;        // 0..75
        const int p   = tid & 7;         // part: samples [64p, 64p+64)
        const int kk  = bin >> 2;        // 0..18
        const int t   = bin & 3;
        const int k   = KLO + kk;
        const int n0  = p << 6;
        const int j0  = (k * n0) & 511;  // exact k*n0 mod 512

        float cr, ci, wc, ws;
        __sincosf((float)j0 * (-2.0f * PI_F / 512.0f), &ci, &cr);  // e^{-2pi i j0/512}
        __sincosf((float)k  * (-2.0f * PI_F / 512.0f), &ws, &wc);  // step e^{-2pi i k/512}

        float re0=0,re1=0,re2=0,re3=0, im0=0,im1=0,im2=0,im3=0;
        const int boff = t * FRM_STRIDE + p * CHK_STRIDE;   // 16B-aligned
        #pragma unroll 8
        for (int i = 0; i < 64; ++i) {
            float4 v = *(const float4*)&xw[boff + 4*i];
            re0 = fmaf(v.x, cr, re0); im0 = fmaf(v.x, ci, im0);
            re1 = fmaf(v.y, cr, re1); im1 = fmaf(v.y, ci, im1);
            re2 = fmaf(v.z, cr, re2); im2 = fmaf(v.z, ci, im2);
            re3 = fmaf(v.w, cr, re3); im3 = fmaf(v.w, ci, im3);
            float nr = fmaf(cr, wc, -(ci * ws));
            float ni = fmaf(cr, ws,  (ci * wc));
            cr = nr; ci = ni;
        }
        // reduce the 8 parts (contiguous lanes)
        #pragma unroll
        for (int mask = 1; mask < 8; mask <<= 1) {
            re0 += __shfl_xor(re0, mask); im0 += __shfl_xor(im0, mask);
            re1 += __shfl_xor(re1, mask); im1 += __shfl_xor(im1, mask);
            re2 += __shfl_xor(re2, mask); im2 += __shfl_xor(im2, mask);
            re3 += __shfl_xor(re3, mask); im3 += __shfl_xor(im3, mask);
        }
        if (p == 0) {
            XsR[kk][t][0] = re0; XsI[kk][t][0] = im0;
            XsR[kk][t][1] = re1; XsI[kk][t][1] = im1;
            XsR[kk][t][2] = re2; XsI[kk][t][2] = im2;
            XsR[kk][t][3] = re3; XsI[kk][t][3] = im3;
        }
    }
    __syncthreads();

    // ---- stage 2: per-frequency ESPRIT on wave 0, then in-wave mean -------
    float asum = 0.0f;
    if (tid < 64) {
        if (tid < NK) {
            cf Xm[NMIC][NTT];
            for (int m = 0; m < NMIC; ++m)
                for (int t = 0; t < NTT; ++t)
                    Xm[m][t] = { XsR[tid][t][m], XsI[tid][t][m] };

            // R = (1/4) Xs Xs^H
            cf R[4][4];
            for (int i = 0; i < 4; ++i)
                for (int j = 0; j < 4; ++j) {
                    cf acc = {0.f, 0.f};
                    for (int t = 0; t < 4; ++t) acc = cadd(acc, cmulc(Xm[i][t], Xm[j][t]));
                    R[i][j] = cscale(acc, 0.25f);
                }

            // one orthogonal-iteration step -> dominant 2-D subspace
            // (phi eigvals similarity-invariant; lam3/lam2 ~ 1e-8 at -80 dB
            //  noise; validated absmax 0.0 in rounds 6/7/8)
            cf Q[4][2], Y[4][2];
            for (int i = 0; i < 4; ++i) { Y[i][0] = R[i][0]; Y[i][1] = R[i][1]; }
            float nrm0 = 0.f;
            for (int i = 0; i < 4; ++i) nrm0 += Y[i][0].x*Y[i][0].x + Y[i][0].y*Y[i][0].y;
            float in0 = __builtin_amdgcn_rsqf(nrm0);
            for (int i = 0; i < 4; ++i) Q[i][0] = cscale(Y[i][0], in0);
            cf pr = {0.f, 0.f};
            for (int i = 0; i < 4; ++i) pr = cadd(pr, cmulc(Y[i][1], Q[i][0]));  // Q0^H Y1
            for (int i = 0; i < 4; ++i) Q[i][1] = csub(Y[i][1], cmul(pr, Q[i][0]));
            float nrm1 = 0.f;
            for (int i = 0; i < 4; ++i) nrm1 += Q[i][1].x*Q[i][1].x + Q[i][1].y*Q[i][1].y;
            float in1 = __builtin_amdgcn_rsqf(nrm1);
            for (int i = 0; i < 4; ++i) Q[i][1] = cscale(Q[i][1], in1);

            // A = s0^H s0 (Hermitian), B = s0^H s1 ; s0 = rows 0..2, s1 = rows 1..3
            float a00 = 0.f, a11 = 0.f;
            cf a01 = {0.f, 0.f};
            cf B[2][2] = { { {0,0}, {0,0} }, { {0,0}, {0,0} } };
            for (int i = 0; i < 3; ++i) {
                a00 += Q[i][0].x*Q[i][0].x + Q[i][0].y*Q[i][0].y;
                a11 += Q[i][1].x*Q[i][1].x + Q[i][1].y*Q[i][1].y;
                a01 = cadd(a01, cmulc(Q[i][1], Q[i][0]));      // conj(Q0)*Q1
                for (int r2 = 0; r2 < 2; ++r2)
                    for (int c2 = 0; c2 < 2; ++c2)
                        B[r2][c2] = cadd(B[r2][c2], cmulc(Q[i+1][c2], Q[i][r2]));
            }
            float detA = a00*a11 - (a01.x*a01.x + a01.y*a01.y);
            float inv  = __builtin_amdgcn_rcpf(detA);
            cf na01  = { -a01.x, -a01.y };
            cf na01c = { -a01.x,  a01.y };
            cf phi00 = cscale(cadd(cscale(B[0][0], a11), cmul(na01,  B[1][0])), inv);
            cf phi01 = cscale(cadd(cscale(B[0][1], a11), cmul(na01,  B[1][1])), inv);
            cf phi10 = cscale(cadd(cmul(na01c, B[0][0]), cscale(B[1][0], a00)), inv);
            cf phi11 = cscale(cadd(cmul(na01c, B[0][1]), cscale(B[1][1], a00)), inv);

            cf tr = cadd(phi00, phi11);
            cf dt = csub(cmul(phi00, phi11), cmul(phi01, phi10));
            cf d2 = csub(cmul(tr, tr), cscale(dt, 4.0f));
            cf disc = csqrtf_c(d2);
            cf lam0 = cscale(cadd(tr, disc), 0.5f);
            cf lam1 = cscale(csub(tr, disc), 0.5f);

            float f     = 31.25f * (float)(KLO + tid);
            float scale = 343.0f / (2.0f * PI_F * f * 0.08f);
            float ph0 = atan2f(lam0.y, lam0.x);
            float ph1 = atan2f(lam1.y, lam1.x);
            float g0 = fminf(fmaxf(ph0 * scale, -1.0f), 1.0f);
            float g1 = fminf(fmaxf(ph1 * scale, -1.0f), 1.0f);
            asum = (asinf(g0) + asinf(g1)) * (180.0f / PI_F);
        }
        // in-wave mean over the 19 bins (lanes >= 19 contribute 0)
        #pragma unroll
        for (int mask = 32; mask >= 1; mask >>= 1)
            asum += __shfl_xor(asum, mask);
        if (tid == 0) out[0] = asum * (1.0f / 38.0f);
    }
}

extern "C" void kernel_launch(void* const* d_in, const int* in_sizes, int n_in,
                              void* d_out, int out_size, void* d_ws, size_t ws_size,
                              hipStream_t stream)
{
    const float* x = (const float*)d_in[0];
    float* out = (float*)d_out;
    esprit_kernel<<<1, 640, 0, stream>>>(x, out);
}